// Round 6
// baseline (229.255 us; speedup 1.0000x reference)
//
#include <hip/hip_runtime.h>

#define BB 16
#define NN 8
#define DD 24
#define HH 48
#define WW 48
#define AA (DD*HH*WW)   // 55296
#define AW (AA/32)      // 1728 words of ignore-bitmask per image
#define TOPKc 7
#define KIGN 189        // (IGNORE_RATIO+1)*TOPK
#define HWORDS 32768    // 65536 bins packed 2 per u32 word, per image

// fixed candidate window (shifted to stay in-grid): 13 x 25 x 25 = 8125
#define WZC 13
#define WYC 25
#define WXC 25
#define WYXC (WYC*WXC)          // 625
#define CNTC (WZC*WYXC)         // 8125
#define CPT 32                  // 32*256 = 8192 >= 8125

struct GT {
  float ctr[3];
  float half_[3];
  float bbox[6];
  float lo[3], hi[3];
  int keep, rejected;
};

struct Accum {
  int   npos[BB];
  float pos_sum[BB];
  float shape_sum, off_sum, iou_sum;
  int   B1[BB];       // level-1 crossing bin (key>>16)
  int   k1[BB];       // residual rank within bin B1 (1-based)
  unsigned Kstar[BB]; // exact key of the k-th largest
  int   neg_cnt[BB];  // count of values with key > Kstar
  float neg_sum[BB];  // sum of those values
};

__device__ __forceinline__ unsigned fkey(float f) {
  unsigned u = __float_as_uint(f);
  return (u & 0x80000000u) ? ~u : (u | 0x80000000u);
}
__device__ __forceinline__ float fkey_inv(unsigned k) {
  return __uint_as_float((k & 0x80000000u) ? (k & 0x7FFFFFFFu) : ~k);
}

// Wave-aggregated packed-histogram add: lanes with equal bin are combined into
// ONE atomic (leader adds popcount). Skewed distributions -> ~1-3 atomics/wave.
// bin < 0 means "no contribution". hist = per-image base, 2 bins per u32 word.
__device__ __forceinline__ void agg_hist_add(unsigned* hist, int bin) {
  const int lane = threadIdx.x & 63;
  unsigned long long todo = __ballot(bin >= 0);
  while (todo) {
    const int leader = __ffsll((unsigned long long)todo) - 1;
    const int lbin = __shfl(bin, leader, 64);
    const unsigned long long eq = __ballot(bin == lbin);
    if (lane == leader) {
      const unsigned add = (unsigned)__popcll(eq & todo) * ((lbin & 1) ? 65536u : 1u);
      atomicAdd(&hist[(unsigned)lbin >> 1], add);
    }
    todo &= ~eq;
  }
}

__device__ __forceinline__ GT prep_gt(const float* __restrict__ p) {
  const float cz=p[0], cy=p[1], cx=p[2], sz=p[3], sy=p[4], sx=p[5], label=p[6];
  const bool has_box = label > -1.0f;
  const float loz = fmaxf(cz - sz*0.5f, 0.0f);
  const float loy = fmaxf(cy - sy*0.5f, 0.0f);
  const float lox = fmaxf(cx - sx*0.5f, 0.0f);
  const float hiz = fminf(cz + sz*0.5f, 96.0f);
  const float hiy = fminf(cy + sy*0.5f, 192.0f);
  const float hix = fminf(cx + sx*0.5f, 192.0f);
  const float nz = fmaxf(hiz - loz, 0.0f);
  const float ny = fmaxf(hiy - loy, 0.0f);
  const float nx = fmaxf(hix - lox, 0.0f);
  const float vol = nz * ny * nx;
  const float percent = vol / (sz * sy * sx);
  const bool good = (percent > 0.1f) && (vol >= 15.0f);
  const bool keep = has_box && (vol > 0.0f) && good;
  const bool rejected = has_box && (vol > 0.0f) && !good;
  GT g;
  const float ncz = loz + nz*0.5f, ncy = loy + ny*0.5f, ncx = lox + nx*0.5f;
  if (keep) {
    g.ctr[0]=ncz*0.25f; g.ctr[1]=ncy*0.25f; g.ctr[2]=ncx*0.25f;
    g.half_[0]=nz*0.5f; g.half_[1]=ny*0.5f; g.half_[2]=nx*0.5f;
    g.bbox[0]=ncz; g.bbox[1]=ncy; g.bbox[2]=ncx;
    g.bbox[3]=nz;  g.bbox[4]=ny;  g.bbox[5]=nx;
  } else {
    for (int j=0;j<3;++j){ g.ctr[j]=-0.25f; g.half_[j]=-0.5f; }
    for (int j=0;j<6;++j) g.bbox[j]=-1.0f;
  }
  g.lo[0]=loz; g.lo[1]=loy; g.lo[2]=lox;
  g.hi[0]=hiz; g.hi[1]=hiy; g.hi[2]=hix;
  g.keep = keep ? 1 : 0;
  g.rejected = rejected ? 1 : 0;
  return g;
}

__device__ __forceinline__ int redI256(int v, int par) {
  __shared__ int s[2][4];
  for (int off = 32; off; off >>= 1) v += __shfl_down(v, off, 64);
  if ((threadIdx.x & 63) == 0) s[par][threadIdx.x >> 6] = v;
  __syncthreads();
  return s[par][0] + s[par][1] + s[par][2] + s[par][3];
}
__device__ __forceinline__ int blockReduceSumI(int v) {
  __shared__ int s[4];
  for (int off = 32; off; off >>= 1) v += __shfl_down(v, off, 64);
  if ((threadIdx.x & 63) == 0) s[threadIdx.x >> 6] = v;
  __syncthreads();
  int r = s[0] + s[1] + s[2] + s[3];
  __syncthreads();
  return r;
}
__device__ __forceinline__ float blockReduceSumF(float v) {
  __shared__ float s[4];
  for (int off = 32; off; off >>= 1) v += __shfl_down(v, off, 64);
  if ((threadIdx.x & 63) == 0) s[threadIdx.x >> 6] = v;
  __syncthreads();
  float r = s[0] + s[1] + s[2] + s[3];
  __syncthreads();
  return r;
}
__device__ __forceinline__ int redI1024(int v) {
  __shared__ int s[16];
  for (int off = 32; off; off >>= 1) v += __shfl_down(v, off, 64);
  if ((threadIdx.x & 63) == 0) s[threadIdx.x >> 6] = v;
  __syncthreads();
  int r = 0;
  #pragma unroll
  for (int w = 0; w < 16; ++w) r += s[w];
  __syncthreads();
  return r;
}
__device__ __forceinline__ float redF1024(float v) {
  __shared__ float s[16];
  for (int off = 32; off; off >>= 1) v += __shfl_down(v, off, 64);
  if ((threadIdx.x & 63) == 0) s[threadIdx.x >> 6] = v;
  __syncthreads();
  float r = 0.0f;
  #pragma unroll
  for (int w = 0; w < 16; ++w) r += s[w];
  __syncthreads();
  return r;
}

#define N_POS4  (BB*AA/4)            // 221184 int4 (pos_n)
#define N_IGN4  (BB*AW/32*8/4)       // ign words = BB*AW ints -> /4
#define N_HIST4 (BB*HWORDS/4)        // 131072 uint4

__global__ __launch_bounds__(256) void k0_init(int4* pos_n4, uint4* ign4,
                                               uint4* hist4, Accum* acc) {
  const int idx = blockIdx.x*256 + threadIdx.x;
  if (idx < N_POS4) {
    pos_n4[idx] = make_int4(0x7FFFFFFF,0x7FFFFFFF,0x7FFFFFFF,0x7FFFFFFF);
  } else if (idx < N_POS4 + (BB*AW)/4) {
    ign4[idx - N_POS4] = make_uint4(0,0,0,0);
  } else {
    hist4[idx - (N_POS4 + (BB*AW)/4)] = make_uint4(0,0,0,0);
  }
  if (idx < BB) {
    acc->npos[idx] = 0; acc->pos_sum[idx] = 0.0f;
    acc->neg_cnt[idx] = 0; acc->neg_sum[idx] = 0.0f;
  }
  if (idx == 0) { acc->shape_sum = 0.0f; acc->off_sum = 0.0f; acc->iou_sum = 0.0f; }
}

// One block per (b,n). Fixed 13x25x25 window (origin clamped in-grid) provably
// contains every anchor at distance <= the 189th-NN radius.
__global__ __launch_bounds__(256, 1) void k2_topk(const float* __restrict__ ann,
                                                  int* __restrict__ pos_n,
                                                  unsigned* __restrict__ ign) {
  const int bn = blockIdx.x;
  const int b = bn >> 3, n = bn & 7;
  const GT g = prep_gt(ann + bn*7);
  if (!g.keep) return;
  const float cz = g.ctr[0], cy = g.ctr[1], cx = g.ctr[2];

  const int rz = (int)floorf(cz + 0.5f);
  const int ry = (int)floorf(cy + 0.5f);
  const int rx = (int)floorf(cx + 0.5f);
  const int zlo = min(max(rz - 6, 0),  DD - WZC);
  const int ylo = min(max(ry - 12, 0), HH - WYC);
  const int xlo = min(max(rx - 12, 0), WW - WXC);

  unsigned kk[CPT];
  int aa_[CPT];
  #pragma unroll
  for (int j = 0; j < CPT; ++j) {
    const int ci = threadIdx.x + j*256;
    const int wz = ci / WYXC;
    const int rem = ci - wz*WYXC;
    const int wy = rem / WXC;
    const int wx = rem - wy*WXC;
    const int z = zlo + wz, y = ylo + wy, x = xlo + wx;
    const float dz = (cz - (float)z) * 2.0f;
    const float dy = cy - (float)y;
    const float dx = cx - (float)x;
    const float d = -__builtin_fmaf(dz, dz, __builtin_fmaf(dy, dy, dx*dx));
    kk[j] = (ci < CNTC) ? fkey(d) : 0u;
    aa_[j] = (z*HH + y)*WW + x;
  }

  unsigned lo7 = 0, hi7 = 0x7FFFFFFFu;
  unsigned lo9 = 0, hi9 = 0x7FFFFFFFu;
  for (int it = 0; it < 31; ++it) {
    const unsigned mid7 = lo7 + (((hi7 - lo7) + 1u) >> 1);
    const unsigned mid9 = lo9 + (((hi9 - lo9) + 1u) >> 1);
    int c7 = 0, c9 = 0;
    #pragma unroll
    for (int j = 0; j < CPT; ++j) {
      c7 += (kk[j] >= mid7);
      c9 += (kk[j] >= mid9);
    }
    const int packed = redI256((c7 << 16) | c9, it & 1);
    c7 = packed >> 16; c9 = packed & 0xFFFF;
    if (lo7 < hi7) { if (c7 >= TOPKc) lo7 = mid7; else hi7 = mid7 - 1; }
    if (lo9 < hi9) { if (c9 >= KIGN)  lo9 = mid9; else hi9 = mid9 - 1; }
  }
  const unsigned k7 = lo7, k9 = lo9;

  __shared__ int tc7, tc9;
  __shared__ int tl7[256], tr7[256];
  __shared__ int tl9[256], tr9[256];
  if (threadIdx.x == 0) { tc7 = 0; tc9 = 0; }
  __syncthreads();
  int cg7l = 0, cg9l = 0;
  #pragma unroll
  for (int j = 0; j < CPT; ++j) {
    const unsigned k = kk[j];
    cg7l += (k > k7);
    cg9l += (k > k9);
    if (k == k7) { int p = atomicAdd(&tc7, 1); if (p < 256) tl7[p] = aa_[j]; }
    if (k == k9 && k9 != k7) { int p = atomicAdd(&tc9, 1); if (p < 256) tl9[p] = aa_[j]; }
  }
  const int packed2 = redI256((cg7l << 16) | cg9l, 1);
  const int cg7 = packed2 >> 16, cg9 = packed2 & 0xFFFF;
  __syncthreads();
  const int T7 = min(tc7, 256), T9 = min(tc9, 256);
  for (int i = threadIdx.x; i < T7; i += 256) {
    int ai = tl7[i], r = 0;
    for (int j = 0; j < T7; ++j) r += (tl7[j] < ai);
    tr7[i] = r;
  }
  for (int i = threadIdx.x; i < T9; i += 256) {
    int ai = tl9[i], r = 0;
    for (int j = 0; j < T9; ++j) r += (tl9[j] < ai);
    tr9[i] = r;
  }
  __syncthreads();

  int* pb = pos_n + (size_t)b*AA;
  unsigned* ib = ign + (size_t)b*AW;
  #pragma unroll
  for (int j = 0; j < CPT; ++j) {
    const unsigned k = kk[j];
    const int a = aa_[j];
    bool top = false, igf = false;
    if (k > k7) top = true;
    else if (k == k7) {
      int r = 0;
      for (int t = 0; t < T7; ++t) if (tl7[t] == a) r = tr7[t];
      const int ov = cg7 + r;
      if (ov < TOPKc) top = true;
      else if (ov < KIGN) igf = true;
    } else if (k > k9) igf = true;
    else if (k == k9) {
      int r = 0;
      for (int t = 0; t < T9; ++t) if (tl9[t] == a) r = tr9[t];
      if (cg9 + r < KIGN) igf = true;
    }
    if (top) atomicMin(&pb[a], n);
    else if (igf) atomicOr(&ib[a >> 5], 1u << (a & 31));
  }
}

// Per-anchor losses + fused level-1 histogram (key>>16) via aggregated atomics.
__global__ __launch_bounds__(256) void k3_loss(
    const float* __restrict__ cls_out, const float* __restrict__ shape_out,
    const float* __restrict__ offset_out, const float* __restrict__ ann,
    const int* __restrict__ pos_n, const unsigned* __restrict__ ignm,
    float* __restrict__ neg, unsigned* __restrict__ hist, Accum* acc) {
  __shared__ GT sg[NN];
  const int idx = blockIdx.x * 256 + threadIdx.x;
  const int b = idx / AA;
  const int a = idx - b * AA;
  if (threadIdx.x < NN) sg[threadIdx.x] = prep_gt(ann + (b*NN + threadIdx.x)*7);
  __syncthreads();
  const int z = a / (HH*WW);
  const int rr = a - z*(HH*WW);
  const int y = rr / WW;
  const int x = rr - y*WW;

  float gign = 0.0f;
  for (int n = 0; n < NN; ++n) {
    if (!sg[n].rejected) continue;
    if ((float)z >= floorf(sg[n].lo[0]) && (float)z < ceilf(sg[n].hi[0]) &&
        (float)y >= floorf(sg[n].lo[1]) && (float)y < ceilf(sg[n].hi[1]) &&
        (float)x >= floorf(sg[n].lo[2]) && (float)x < ceilf(sg[n].hi[2])) gign = -1.0f;
  }

  const int pn = pos_n[idx];
  const bool is_pos = (pn < NN);
  const float target = is_pos ? 1.0f : 0.0f;
  const int ibit = (ignm[b*AW + (a >> 5)] >> (a & 31)) & 1;
  const float ignore = (ibit ? -1.0f : 0.0f) + gign;
  const float pred = cls_out[idx];
  float prob = 1.0f / (1.0f + expf(-pred));
  prob = fminf(fmaxf(prob, 1e-4f), 1.0f - 1e-4f);
  const float alpha_f = is_pos ? 0.75f : 0.25f;
  const float pt = is_pos ? (1.0f - prob) : prob;
  const float fw = alpha_f * pt * pt;
  const float bce = fmaxf(pred, 0.0f) + log1pf(expf(-fabsf(pred))) - pred * target;
  float loss = (ignore == 0.0f) ? fw * bce : 0.0f;
  if (prob < 0.8f && is_pos) loss *= 4.0f;
  const float nval = is_pos ? -1.0f : loss;
  neg[idx] = nval;

  // fused level-1 histogram (uniform control flow here; all lanes contribute)
  agg_hist_add(hist + (size_t)b*HWORDS, (int)(fkey(nval) >> 16));

  const int np = blockReduceSumI(is_pos ? 1 : 0);
  const float ps = blockReduceSumF(is_pos ? loss : 0.0f);
  if (threadIdx.x == 0 && np) {
    atomicAdd(&acc->npos[b], np);
    atomicAdd(&acc->pos_sum[b], ps);
  }

  if (is_pos) {
    const GT& g = sg[pn];
    const float toz = g.ctr[0] - (float)z;
    const float toy = g.ctr[1] - (float)y;
    const float tox = g.ctr[2] - (float)x;
    const float poz = offset_out[((size_t)b*3 + 0)*AA + a];
    const float poy = offset_out[((size_t)b*3 + 1)*AA + a];
    const float pox = offset_out[((size_t)b*3 + 2)*AA + a];
    const float psz = shape_out[((size_t)b*3 + 0)*AA + a];
    const float psy = shape_out[((size_t)b*3 + 1)*AA + a];
    const float psx = shape_out[((size_t)b*3 + 2)*AA + a];
    const float off_t = fabsf(poz - toz) + fabsf(poy - toy) + fabsf(pox - tox);
    const float shp_t = fabsf(psz - g.half_[0]) + fabsf(psy - g.half_[1]) + fabsf(psx - g.half_[2]);
    const float c1z = ((float)z + poz) * 4.0f;
    const float c1y = ((float)y + poy) * 4.0f;
    const float c1x = ((float)x + pox) * 4.0f;
    const float s1z = 2.0f*psz, s1y = 2.0f*psy, s1x = 2.0f*psx;
    const float lo1z = c1z - s1z*0.5f, hi1z = c1z + s1z*0.5f;
    const float lo1y = c1y - s1y*0.5f, hi1y = c1y + s1y*0.5f;
    const float lo1x = c1x - s1x*0.5f, hi1x = c1x + s1x*0.5f;
    const float c2z = g.bbox[0], c2y = g.bbox[1], c2x = g.bbox[2];
    const float s2z = g.bbox[3], s2y = g.bbox[4], s2x = g.bbox[5];
    const float lo2z = c2z - s2z*0.5f, hi2z = c2z + s2z*0.5f;
    const float lo2y = c2y - s2y*0.5f, hi2y = c2y + s2y*0.5f;
    const float lo2x = c2x - s2x*0.5f, hi2x = c2x + s2x*0.5f;
    const float iz = fmaxf(fminf(hi1z,hi2z) - fmaxf(lo1z,lo2z), 0.0f);
    const float iy = fmaxf(fminf(hi1y,hi2y) - fmaxf(lo1y,lo2y), 0.0f);
    const float ix = fmaxf(fminf(hi1x,hi2x) - fmaxf(lo1x,lo2x), 0.0f);
    const float inter = iz*iy*ix + 1e-7f;
    const float uni = s1z*s1y*s1x + s2z*s2y*s2x - inter;
    const float iou = inter / uni;
    const float ez = fmaxf(hi1z,hi2z) - fminf(lo1z,lo2z);
    const float ey = fmaxf(hi1y,hi2y) - fminf(lo1y,lo2y);
    const float ex = fmaxf(hi1x,hi2x) - fminf(lo1x,lo2x);
    const float c2d = (ez*ez + ey*ey) + ex*ex + 1e-7f;
    const float rz2 = (lo2z + hi2z) - (lo1z + hi1z);
    const float ry2 = (lo2y + hi2y) - (lo1y + hi1y);
    const float rx2 = (lo2x + hi2x) - (lo1x + hi1x);
    const float rho2 = ((rz2*rz2 + ry2*ry2) + rx2*rx2) * 0.25f;
    const float diou = iou - rho2 / c2d;
    atomicAdd(&acc->shape_sum, shp_t);
    atomicAdd(&acc->off_sum, off_t);
    atomicAdd(&acc->iou_sum, diou);
  }
}

// One block per image: suffix-scan of 65536 packed bins, find crossing bin and
// residual rank; zero the hist behind itself (so the buffer is reusable).
__global__ __launch_bounds__(1024) void ks_scan(unsigned* __restrict__ hist,
                                                Accum* acc, int level) {
  const int b = blockIdx.x;
  unsigned* hb = hist + (size_t)b*HWORDS;
  const int tid = threadIdx.x, lane = tid & 63, wave = tid >> 6;
  int k;
  if (level == 1) { const int npos = acc->npos[b]; k = npos > 0 ? 100*npos : 100; }
  else k = acc->k1[b];

  // each thread covers bins [tid*64, tid*64+64) = words [tid*32, tid*32+32)
  int csum = 0;
  #pragma unroll
  for (int i = 0; i < 8; ++i) {
    const uint4 v = ((const uint4*)hb)[tid*8 + i];
    csum += (int)((v.x & 0xFFFFu) + (v.x >> 16) + (v.y & 0xFFFFu) + (v.y >> 16)
                + (v.z & 0xFFFFu) + (v.z >> 16) + (v.w & 0xFFFFu) + (v.w >> 16));
  }

  __shared__ int wt[16];
  int S = csum;
  #pragma unroll
  for (int off = 1; off < 64; off <<= 1) {
    const int t = __shfl_down(S, off, 64);
    if (lane + off < 64) S += t;
  }
  if (lane == 0) wt[wave] = S;
  __syncthreads();
  int above = 0;
  for (int ww = wave + 1; ww < 16; ++ww) above += wt[ww];
  const int sfx = above + (S - csum);   // count in bins strictly above this thread's range

  if (sfx < k && sfx + csum >= k) {     // unique crossing thread (csum > 0)
    int running = sfx;
    for (int i = 63; i >= 0; --i) {
      const unsigned word = hb[tid*32 + (i >> 1)];
      const int c = (i & 1) ? (int)(word >> 16) : (int)(word & 0xFFFFu);
      if (running + c >= k) {
        const int bin = tid*64 + i;
        if (level == 1) { acc->B1[b] = bin; acc->k1[b] = k - running; }
        else            { acc->Kstar[b] = ((unsigned)acc->B1[b] << 16) | (unsigned)bin; }
        break;
      }
      running += c;
    }
  }
  // zero own words (own scan above reads only own words, in program order)
  #pragma unroll
  for (int i = 0; i < 8; ++i) ((uint4*)hb)[tid*8 + i] = make_uint4(0,0,0,0);
}

// Whole-chip pass: level-2 histogram (low 16 key bits) among keys matching B1.
__global__ __launch_bounds__(1024) void kh2(const float* __restrict__ neg,
                                            unsigned* __restrict__ hist,
                                            const Accum* __restrict__ acc) {
  const int bid = blockIdx.x;
  const int b = bid / 54;
  const int i = (bid - b*54)*1024 + threadIdx.x;
  const unsigned key = fkey(neg[(size_t)b*AA + i]);
  const int B1 = acc->B1[b];
  const int bin = ((int)(key >> 16) == B1) ? (int)(key & 0xFFFFu) : -1;
  agg_hist_add(hist + (size_t)b*HWORDS, bin);
}

// Whole-chip pass: count/sum of values strictly above the k-th key.
__global__ __launch_bounds__(1024) void k4_sum(const float* __restrict__ neg,
                                               Accum* acc) {
  const int bid = blockIdx.x;
  const int b = bid / 54;
  const int i = (bid - b*54)*1024 + threadIdx.x;
  const float xv = neg[(size_t)b*AA + i];
  const bool gt = fkey(xv) > acc->Kstar[b];
  const int cg = redI1024(gt ? 1 : 0);
  const float sg = redF1024(gt ? xv : 0.0f);
  if (threadIdx.x == 0) {
    atomicAdd(&acc->neg_cnt[b], cg);
    atomicAdd(&acc->neg_sum[b], sg);
  }
}

__global__ void k5_final(const Accum* __restrict__ acc, float* __restrict__ out) {
  float s = 0.0f; int tot = 0;
  for (int b = 0; b < BB; ++b) {
    const int npos = acc->npos[b];
    const int k = npos > 0 ? 100*npos : 100;
    const float v = fkey_inv(acc->Kstar[b]);
    const float sg = acc->neg_sum[b];
    const int cg = acc->neg_cnt[b];
    const float ns = (v >= 0.0f) ? (sg + (float)(k - cg) * v) : sg;
    s += (acc->pos_sum[b] + ns) / fmaxf((float)npos, 1.0f);
    tot += npos;
  }
  out[0] = s / (float)BB;
  const float denom = fmaxf((float)tot, 1.0f);
  out[1] = acc->shape_sum / (denom * 3.0f);
  out[2] = acc->off_sum / (denom * 3.0f);
  out[3] = 1.0f - acc->iou_sum / denom;
}

extern "C" void kernel_launch(void* const* d_in, const int* in_sizes, int n_in,
                              void* d_out, int out_size, void* d_ws, size_t ws_size,
                              hipStream_t stream) {
  const float* cls_out    = (const float*)d_in[0];
  const float* shape_out  = (const float*)d_in[1];
  const float* offset_out = (const float*)d_in[2];
  const float* ann        = (const float*)d_in[3];
  float* out = (float*)d_out;

  char* ws = (char*)d_ws;
  Accum* acc    = (Accum*)ws;                              // < 1 KB
  int* pos_n    = (int*)(ws + 1024);                       // 3.54 MB
  unsigned* ign = (unsigned*)(pos_n + (size_t)BB*AA);      // 110.6 KB
  float* neg    = (float*)(ign + (size_t)BB*AW);           // 3.54 MB
  unsigned* hist= (unsigned*)(neg + (size_t)BB*AA);        // 2 MB (packed 64K bins)

  const int n0 = N_POS4 + (BB*AW)/4 + N_HIST4;             // 359168 int4 slots
  hipLaunchKernelGGL(k0_init, dim3(n0/256), dim3(256), 0, stream,
                     (int4*)pos_n, (uint4*)ign, (uint4*)hist, acc);
  hipLaunchKernelGGL(k2_topk, dim3(BB*NN), dim3(256), 0, stream, ann, pos_n, ign);
  hipLaunchKernelGGL(k3_loss, dim3((BB*AA)/256), dim3(256), 0, stream,
                     cls_out, shape_out, offset_out, ann, pos_n, ign, neg, hist, acc);
  hipLaunchKernelGGL(ks_scan, dim3(BB), dim3(1024), 0, stream, hist, acc, 1);
  hipLaunchKernelGGL(kh2, dim3(BB*54), dim3(1024), 0, stream, neg, hist, acc);
  hipLaunchKernelGGL(ks_scan, dim3(BB), dim3(1024), 0, stream, hist, acc, 2);
  hipLaunchKernelGGL(k4_sum, dim3(BB*54), dim3(1024), 0, stream, neg, acc);
  hipLaunchKernelGGL(k5_final, dim3(1), dim3(1), 0, stream, acc, out);
}

// Round 7
// 209.809 us; speedup vs baseline: 1.0927x; 1.0927x over previous
//
#include <hip/hip_runtime.h>

#define BB 16
#define NN 8
#define DD 24
#define HH 48
#define WW 48
#define AA (DD*HH*WW)   // 55296
#define AW (AA/32)      // 1728 ignore-bitmask words per image
#define TOPKc 7
#define KIGN 189        // (IGNORE_RATIO+1)*TOPK
#define NB1 2048        // level-1 bins = key >> 21

// fixed candidate window (shifted to stay in-grid): 13 x 25 x 25 = 8125
#define WZC 13
#define WYC 25
#define WXC 25
#define WYXC (WYC*WXC)          // 625
#define CNTC (WZC*WYXC)         // 8125
#define CPT 32                  // 32*256 = 8192 >= 8125

struct GT {
  float ctr[3];
  float half_[3];
  float bbox[6];
  float lo[3], hi[3];
  int keep, rejected;
};

struct Accum {
  int   npos[BB];
  float pos_sum[BB];
  float shape_sum, off_sum, iou_sum;
  int   B1[BB];        // level-1 crossing bin (key>>21)
  int   cnt_above[BB]; // # elems in bins strictly above B1
  float sum_above[BB]; // sum of values in bins > B1 (nonneg values only)
  int   list_cnt[BB];  // survivor count (bin == B1)
  float per_img[BB];
};

__device__ __forceinline__ unsigned fkey(float f) {
  unsigned u = __float_as_uint(f);
  return (u & 0x80000000u) ? ~u : (u | 0x80000000u);
}
__device__ __forceinline__ float fkey_inv(unsigned k) {
  return __uint_as_float((k & 0x80000000u) ? (k & 0x7FFFFFFFu) : ~k);
}

// Wave-aggregated LDS histogram add: lanes with equal bin combine into one
// atomic (leader adds popcount). bin < 0 = no contribution.
__device__ __forceinline__ void agg_lds_add(int* h, int bin) {
  const int lane = threadIdx.x & 63;
  unsigned long long todo = __ballot(bin >= 0);
  while (todo) {
    const int leader = __ffsll((unsigned long long)todo) - 1;
    const int lbin = __shfl(bin, leader, 64);
    const unsigned long long eq = __ballot(bin == lbin) & todo;
    if (lane == leader) atomicAdd(&h[lbin], (int)__popcll(eq));
    todo &= ~eq;
  }
}

__device__ __forceinline__ GT prep_gt(const float* __restrict__ p) {
  const float cz=p[0], cy=p[1], cx=p[2], sz=p[3], sy=p[4], sx=p[5], label=p[6];
  const bool has_box = label > -1.0f;
  const float loz = fmaxf(cz - sz*0.5f, 0.0f);
  const float loy = fmaxf(cy - sy*0.5f, 0.0f);
  const float lox = fmaxf(cx - sx*0.5f, 0.0f);
  const float hiz = fminf(cz + sz*0.5f, 96.0f);
  const float hiy = fminf(cy + sy*0.5f, 192.0f);
  const float hix = fminf(cx + sx*0.5f, 192.0f);
  const float nz = fmaxf(hiz - loz, 0.0f);
  const float ny = fmaxf(hiy - loy, 0.0f);
  const float nx = fmaxf(hix - lox, 0.0f);
  const float vol = nz * ny * nx;
  const float percent = vol / (sz * sy * sx);
  const bool good = (percent > 0.1f) && (vol >= 15.0f);
  const bool keep = has_box && (vol > 0.0f) && good;
  const bool rejected = has_box && (vol > 0.0f) && !good;
  GT g;
  const float ncz = loz + nz*0.5f, ncy = loy + ny*0.5f, ncx = lox + nx*0.5f;
  if (keep) {
    g.ctr[0]=ncz*0.25f; g.ctr[1]=ncy*0.25f; g.ctr[2]=ncx*0.25f;
    g.half_[0]=nz*0.5f; g.half_[1]=ny*0.5f; g.half_[2]=nx*0.5f;
    g.bbox[0]=ncz; g.bbox[1]=ncy; g.bbox[2]=ncx;
    g.bbox[3]=nz;  g.bbox[4]=ny;  g.bbox[5]=nx;
  } else {
    for (int j=0;j<3;++j){ g.ctr[j]=-0.25f; g.half_[j]=-0.5f; }
    for (int j=0;j<6;++j) g.bbox[j]=-1.0f;
  }
  g.lo[0]=loz; g.lo[1]=loy; g.lo[2]=lox;
  g.hi[0]=hiz; g.hi[1]=hiy; g.hi[2]=hix;
  g.keep = keep ? 1 : 0;
  g.rejected = rejected ? 1 : 0;
  return g;
}

__device__ __forceinline__ int redI256(int v, int par) {
  __shared__ int s[2][4];
  for (int off = 32; off; off >>= 1) v += __shfl_down(v, off, 64);
  if ((threadIdx.x & 63) == 0) s[par][threadIdx.x >> 6] = v;
  __syncthreads();
  return s[par][0] + s[par][1] + s[par][2] + s[par][3];
}
__device__ __forceinline__ int blockReduceSumI(int v) {
  __shared__ int s[4];
  for (int off = 32; off; off >>= 1) v += __shfl_down(v, off, 64);
  if ((threadIdx.x & 63) == 0) s[threadIdx.x >> 6] = v;
  __syncthreads();
  int r = s[0] + s[1] + s[2] + s[3];
  __syncthreads();
  return r;
}
__device__ __forceinline__ float blockReduceSumF(float v) {
  __shared__ float s[4];
  for (int off = 32; off; off >>= 1) v += __shfl_down(v, off, 64);
  if ((threadIdx.x & 63) == 0) s[threadIdx.x >> 6] = v;
  __syncthreads();
  float r = s[0] + s[1] + s[2] + s[3];
  __syncthreads();
  return r;
}
__device__ __forceinline__ int redI1024(int v) {
  __shared__ int s[16];
  for (int off = 32; off; off >>= 1) v += __shfl_down(v, off, 64);
  if ((threadIdx.x & 63) == 0) s[threadIdx.x >> 6] = v;
  __syncthreads();
  int r = 0;
  #pragma unroll
  for (int w = 0; w < 16; ++w) r += s[w];
  __syncthreads();
  return r;
}
__device__ __forceinline__ float redF1024(float v) {
  __shared__ float s[16];
  for (int off = 32; off; off >>= 1) v += __shfl_down(v, off, 64);
  if ((threadIdx.x & 63) == 0) s[threadIdx.x >> 6] = v;
  __syncthreads();
  float r = 0.0f;
  #pragma unroll
  for (int w = 0; w < 16; ++w) r += s[w];
  __syncthreads();
  return r;
}

// 1024-thread suffix-find over nbins (1024 or 2048) LDS bins.
// Writes (crossing thread only): *s_bin = bin, *s_cnt = count strictly above.
__device__ void suffix_find_1024(const int* h, int nbins, int ktarget,
                                 int* s_bin, int* s_cnt) {
  const int tid = threadIdx.x, lane = tid & 63, wave = tid >> 6;
  const int C = nbins >> 10;   // bins per thread: 1 or 2
  int csum = 0;
  for (int i = 0; i < C; ++i) csum += h[tid*C + i];
  __shared__ int wt[16];
  int S = csum;
  #pragma unroll
  for (int off = 1; off < 64; off <<= 1) {
    const int t = __shfl_down(S, off, 64);
    if (lane + off < 64) S += t;
  }
  if (lane == 0) wt[wave] = S;
  __syncthreads();
  int above = 0;
  for (int w = wave + 1; w < 16; ++w) above += wt[w];
  const int sfx = above + (S - csum);
  if (sfx < ktarget && sfx + csum >= ktarget) {
    int running = sfx;
    for (int i = C - 1; i >= 0; --i) {
      const int c = h[tid*C + i];
      if (running + c >= ktarget) { *s_bin = tid*C + i; *s_cnt = running; break; }
      running += c;
    }
  }
  __syncthreads();
}

#define N_POS4  (BB*AA/4)       // 221184
#define N_IGN4  (BB*AW/4)       // 6912
#define N_HIST4 (BB*NB1/4)      // 8192

__global__ __launch_bounds__(256) void k0_init(int4* pos_n4, uint4* ign4,
                                               int4* hist4, Accum* acc) {
  const int idx = blockIdx.x*256 + threadIdx.x;
  if (idx < N_POS4) {
    pos_n4[idx] = make_int4(0x7FFFFFFF,0x7FFFFFFF,0x7FFFFFFF,0x7FFFFFFF);
  } else if (idx < N_POS4 + N_IGN4) {
    ign4[idx - N_POS4] = make_uint4(0,0,0,0);
  } else if (idx < N_POS4 + N_IGN4 + N_HIST4) {
    hist4[idx - (N_POS4 + N_IGN4)] = make_int4(0,0,0,0);
  }
  if (idx < BB) {
    acc->npos[idx] = 0; acc->pos_sum[idx] = 0.0f;
    acc->B1[idx] = 0; acc->cnt_above[idx] = 0;
    acc->sum_above[idx] = 0.0f; acc->list_cnt[idx] = 0;
    acc->per_img[idx] = 0.0f;
  }
  if (idx == 0) { acc->shape_sum = 0.0f; acc->off_sum = 0.0f; acc->iou_sum = 0.0f; }
}

// One block per (b,n). Fixed 13x25x25 window (origin clamped in-grid) provably
// contains every anchor at distance <= the 189th-NN radius.
__global__ __launch_bounds__(256, 1) void k2_topk(const float* __restrict__ ann,
                                                  int* __restrict__ pos_n,
                                                  unsigned* __restrict__ ign) {
  const int bn = blockIdx.x;
  const int b = bn >> 3, n = bn & 7;
  const GT g = prep_gt(ann + bn*7);
  if (!g.keep) return;
  const float cz = g.ctr[0], cy = g.ctr[1], cx = g.ctr[2];

  const int rz = (int)floorf(cz + 0.5f);
  const int ry = (int)floorf(cy + 0.5f);
  const int rx = (int)floorf(cx + 0.5f);
  const int zlo = min(max(rz - 6, 0),  DD - WZC);
  const int ylo = min(max(ry - 12, 0), HH - WYC);
  const int xlo = min(max(rx - 12, 0), WW - WXC);

  unsigned kk[CPT];
  int aa_[CPT];
  #pragma unroll
  for (int j = 0; j < CPT; ++j) {
    const int ci = threadIdx.x + j*256;
    const int wz = ci / WYXC;
    const int rem = ci - wz*WYXC;
    const int wy = rem / WXC;
    const int wx = rem - wy*WXC;
    const int z = zlo + wz, y = ylo + wy, x = xlo + wx;
    const float dz = (cz - (float)z) * 2.0f;
    const float dy = cy - (float)y;
    const float dx = cx - (float)x;
    const float d = -__builtin_fmaf(dz, dz, __builtin_fmaf(dy, dy, dx*dx));
    kk[j] = (ci < CNTC) ? fkey(d) : 0u;
    aa_[j] = (z*HH + y)*WW + x;
  }

  unsigned lo7 = 0, hi7 = 0x7FFFFFFFu;
  unsigned lo9 = 0, hi9 = 0x7FFFFFFFu;
  for (int it = 0; it < 31; ++it) {
    const unsigned mid7 = lo7 + (((hi7 - lo7) + 1u) >> 1);
    const unsigned mid9 = lo9 + (((hi9 - lo9) + 1u) >> 1);
    int c7 = 0, c9 = 0;
    #pragma unroll
    for (int j = 0; j < CPT; ++j) {
      c7 += (kk[j] >= mid7);
      c9 += (kk[j] >= mid9);
    }
    const int packed = redI256((c7 << 16) | c9, it & 1);
    c7 = packed >> 16; c9 = packed & 0xFFFF;
    if (lo7 < hi7) { if (c7 >= TOPKc) lo7 = mid7; else hi7 = mid7 - 1; }
    if (lo9 < hi9) { if (c9 >= KIGN)  lo9 = mid9; else hi9 = mid9 - 1; }
  }
  const unsigned k7 = lo7, k9 = lo9;

  __shared__ int tc7, tc9;
  __shared__ int tl7[256], tr7[256];
  __shared__ int tl9[256], tr9[256];
  if (threadIdx.x == 0) { tc7 = 0; tc9 = 0; }
  __syncthreads();
  int cg7l = 0, cg9l = 0;
  #pragma unroll
  for (int j = 0; j < CPT; ++j) {
    const unsigned k = kk[j];
    cg7l += (k > k7);
    cg9l += (k > k9);
    if (k == k7) { int p = atomicAdd(&tc7, 1); if (p < 256) tl7[p] = aa_[j]; }
    if (k == k9 && k9 != k7) { int p = atomicAdd(&tc9, 1); if (p < 256) tl9[p] = aa_[j]; }
  }
  const int packed2 = redI256((cg7l << 16) | cg9l, 1);
  const int cg7 = packed2 >> 16, cg9 = packed2 & 0xFFFF;
  __syncthreads();
  const int T7 = min(tc7, 256), T9 = min(tc9, 256);
  for (int i = threadIdx.x; i < T7; i += 256) {
    int ai = tl7[i], r = 0;
    for (int j = 0; j < T7; ++j) r += (tl7[j] < ai);
    tr7[i] = r;
  }
  for (int i = threadIdx.x; i < T9; i += 256) {
    int ai = tl9[i], r = 0;
    for (int j = 0; j < T9; ++j) r += (tl9[j] < ai);
    tr9[i] = r;
  }
  __syncthreads();

  int* pb = pos_n + (size_t)b*AA;
  unsigned* ib = ign + (size_t)b*AW;
  #pragma unroll
  for (int j = 0; j < CPT; ++j) {
    const unsigned k = kk[j];
    const int a = aa_[j];
    bool top = false, igf = false;
    if (k > k7) top = true;
    else if (k == k7) {
      int r = 0;
      for (int t = 0; t < T7; ++t) if (tl7[t] == a) r = tr7[t];
      const int ov = cg7 + r;
      if (ov < TOPKc) top = true;
      else if (ov < KIGN) igf = true;
    } else if (k > k9) igf = true;
    else if (k == k9) {
      int r = 0;
      for (int t = 0; t < T9; ++t) if (tl9[t] == a) r = tr9[t];
      if (cg9 + r < KIGN) igf = true;
    }
    if (top) atomicMin(&pb[a], n);
    else if (igf) atomicOr(&ib[a >> 5], 1u << (a & 31));
  }
}

// Per-anchor losses + PER-BLOCK LDS level-1 histogram, sparse-merged to global.
__global__ __launch_bounds__(256) void k3_loss(
    const float* __restrict__ cls_out, const float* __restrict__ shape_out,
    const float* __restrict__ offset_out, const float* __restrict__ ann,
    const int* __restrict__ pos_n, const unsigned* __restrict__ ignm,
    float* __restrict__ neg, int* __restrict__ ghist, Accum* acc) {
  __shared__ GT sg[NN];
  __shared__ int h1[NB1];
  const int idx = blockIdx.x * 256 + threadIdx.x;
  const int b = idx / AA;            // AA%256==0 -> block-uniform
  const int a = idx - b * AA;
  if (threadIdx.x < NN) sg[threadIdx.x] = prep_gt(ann + (b*NN + threadIdx.x)*7);
  #pragma unroll
  for (int i = 0; i < NB1/256; ++i) h1[threadIdx.x + i*256] = 0;
  __syncthreads();
  const int z = a / (HH*WW);
  const int rr = a - z*(HH*WW);
  const int y = rr / WW;
  const int x = rr - y*WW;

  float gign = 0.0f;
  for (int n = 0; n < NN; ++n) {
    if (!sg[n].rejected) continue;
    if ((float)z >= floorf(sg[n].lo[0]) && (float)z < ceilf(sg[n].hi[0]) &&
        (float)y >= floorf(sg[n].lo[1]) && (float)y < ceilf(sg[n].hi[1]) &&
        (float)x >= floorf(sg[n].lo[2]) && (float)x < ceilf(sg[n].hi[2])) gign = -1.0f;
  }

  const int pn = pos_n[idx];
  const bool is_pos = (pn < NN);
  const float target = is_pos ? 1.0f : 0.0f;
  const int ibit = (ignm[b*AW + (a >> 5)] >> (a & 31)) & 1;
  const float ignore = (ibit ? -1.0f : 0.0f) + gign;
  const float pred = cls_out[idx];
  float prob = 1.0f / (1.0f + expf(-pred));
  prob = fminf(fmaxf(prob, 1e-4f), 1.0f - 1e-4f);
  const float alpha_f = is_pos ? 0.75f : 0.25f;
  const float pt = is_pos ? (1.0f - prob) : prob;
  const float fw = alpha_f * pt * pt;
  const float bce = fmaxf(pred, 0.0f) + log1pf(expf(-fabsf(pred))) - pred * target;
  float loss = (ignore == 0.0f) ? fw * bce : 0.0f;
  if (prob < 0.8f && is_pos) loss *= 4.0f;
  const float nval = is_pos ? -1.0f : loss;
  neg[idx] = nval;

  // LDS level-1 histogram (all lanes active & uniform here)
  agg_lds_add(h1, (int)(fkey(nval) >> 21));

  const int np = blockReduceSumI(is_pos ? 1 : 0);
  const float ps = blockReduceSumF(is_pos ? loss : 0.0f);
  if (threadIdx.x == 0 && np) {
    atomicAdd(&acc->npos[b], np);
    atomicAdd(&acc->pos_sum[b], ps);
  }

  if (is_pos) {
    const GT& g = sg[pn];
    const float toz = g.ctr[0] - (float)z;
    const float toy = g.ctr[1] - (float)y;
    const float tox = g.ctr[2] - (float)x;
    const float poz = offset_out[((size_t)b*3 + 0)*AA + a];
    const float poy = offset_out[((size_t)b*3 + 1)*AA + a];
    const float pox = offset_out[((size_t)b*3 + 2)*AA + a];
    const float psz = shape_out[((size_t)b*3 + 0)*AA + a];
    const float psy = shape_out[((size_t)b*3 + 1)*AA + a];
    const float psx = shape_out[((size_t)b*3 + 2)*AA + a];
    const float off_t = fabsf(poz - toz) + fabsf(poy - toy) + fabsf(pox - tox);
    const float shp_t = fabsf(psz - g.half_[0]) + fabsf(psy - g.half_[1]) + fabsf(psx - g.half_[2]);
    const float c1z = ((float)z + poz) * 4.0f;
    const float c1y = ((float)y + poy) * 4.0f;
    const float c1x = ((float)x + pox) * 4.0f;
    const float s1z = 2.0f*psz, s1y = 2.0f*psy, s1x = 2.0f*psx;
    const float lo1z = c1z - s1z*0.5f, hi1z = c1z + s1z*0.5f;
    const float lo1y = c1y - s1y*0.5f, hi1y = c1y + s1y*0.5f;
    const float lo1x = c1x - s1x*0.5f, hi1x = c1x + s1x*0.5f;
    const float c2z = g.bbox[0], c2y = g.bbox[1], c2x = g.bbox[2];
    const float s2z = g.bbox[3], s2y = g.bbox[4], s2x = g.bbox[5];
    const float lo2z = c2z - s2z*0.5f, hi2z = c2z + s2z*0.5f;
    const float lo2y = c2y - s2y*0.5f, hi2y = c2y + s2y*0.5f;
    const float lo2x = c2x - s2x*0.5f, hi2x = c2x + s2x*0.5f;
    const float iz = fmaxf(fminf(hi1z,hi2z) - fmaxf(lo1z,lo2z), 0.0f);
    const float iy = fmaxf(fminf(hi1y,hi2y) - fmaxf(lo1y,lo2y), 0.0f);
    const float ix = fmaxf(fminf(hi1x,hi2x) - fmaxf(lo1x,lo2x), 0.0f);
    const float inter = iz*iy*ix + 1e-7f;
    const float uni = s1z*s1y*s1x + s2z*s2y*s2x - inter;
    const float iou = inter / uni;
    const float ez = fmaxf(hi1z,hi2z) - fminf(lo1z,lo2z);
    const float ey = fmaxf(hi1y,hi2y) - fminf(lo1y,lo2y);
    const float ex = fmaxf(hi1x,hi2x) - fminf(lo1x,lo2x);
    const float c2d = (ez*ez + ey*ey) + ex*ex + 1e-7f;
    const float rz2 = (lo2z + hi2z) - (lo1z + hi1z);
    const float ry2 = (lo2y + hi2y) - (lo1y + hi1y);
    const float rx2 = (lo2x + hi2x) - (lo1x + hi1x);
    const float rho2 = ((rz2*rz2 + ry2*ry2) + rx2*rx2) * 0.25f;
    const float diou = iou - rho2 / c2d;
    atomicAdd(&acc->shape_sum, shp_t);
    atomicAdd(&acc->off_sum, off_t);
    atomicAdd(&acc->iou_sum, diou);
  }

  __syncthreads();
  // sparse merge: only nonzero bins (few per block) hit global atomics
  #pragma unroll
  for (int i = 0; i < NB1/256; ++i) {
    const int bin = threadIdx.x + i*256;
    const int c = h1[bin];
    if (c) atomicAdd(&ghist[b*NB1 + bin], c);
  }
}

// One block per image: suffix-scan of 2048 bins -> B1 + exact count above.
__global__ __launch_bounds__(256) void ks1(const int* __restrict__ ghist, Accum* acc) {
  const int b = blockIdx.x;
  const int* hb = ghist + b*NB1;
  const int tid = threadIdx.x, lane = tid & 63, wave = tid >> 6;
  const int npos = acc->npos[b];
  const int k = npos > 0 ? 100*npos : 100;
  int csum = 0;
  #pragma unroll
  for (int i = 0; i < 8; ++i) csum += hb[tid*8 + i];
  __shared__ int wt[4];
  int S = csum;
  #pragma unroll
  for (int off = 1; off < 64; off <<= 1) {
    const int t = __shfl_down(S, off, 64);
    if (lane + off < 64) S += t;
  }
  if (lane == 0) wt[wave] = S;
  __syncthreads();
  int above = 0;
  for (int w = wave + 1; w < 4; ++w) above += wt[w];
  const int sfx = above + (S - csum);
  if (sfx < k && sfx + csum >= k) {
    int running = sfx;
    for (int i = 7; i >= 0; --i) {
      const int c = hb[tid*8 + i];
      if (running + c >= k) {
        acc->B1[b] = tid*8 + i;
        acc->cnt_above[b] = running;
        break;
      }
      running += c;
    }
  }
}

// Full-chip: sum values above bin B1 (nonneg only) + compact bin-B1 survivors.
__global__ __launch_bounds__(256) void kgather(const float* __restrict__ neg,
                                               float* __restrict__ list, Accum* acc) {
  const int idx = blockIdx.x*256 + threadIdx.x;
  const int b = idx / AA;
  const int lane = threadIdx.x & 63;
  const int B1 = acc->B1[b];
  const float val = neg[idx];
  const int bin = (int)(fkey(val) >> 21);
  const float sA = (bin > B1 && bin >= 1024) ? val : 0.0f;   // bin>=1024 <=> val>=0
  const float bs = blockReduceSumF(sA);
  if (threadIdx.x == 0 && bs != 0.0f) atomicAdd(&acc->sum_above[b], bs);

  const bool match = (B1 >= 1024) && (bin == B1);
  const unsigned long long mask = __ballot(match);
  if (match) {
    const int leader = __ffsll(mask) - 1;
    int base = 0;
    if (lane == leader) base = atomicAdd(&acc->list_cnt[b], (int)__popcll(mask));
    base = __shfl(base, leader, 64);
    const int pos = (int)__popcll(mask & ((1ull << lane) - 1ull));
    list[(size_t)b*AA + base + pos] = val;
  }
}

// One block per image: exact refinement of remaining 21 key bits over the
// survivor list (L2-resident, small), then final ns with reference tie rules.
__global__ __launch_bounds__(1024) void ksel(const float* __restrict__ list, Accum* acc) {
  const int b = blockIdx.x;
  const int tid = threadIdx.x;
  const int npos = acc->npos[b];
  const int k = npos > 0 ? 100*npos : 100;
  const int B1 = acc->B1[b];
  const float pos_sum = acc->pos_sum[b];
  const float sum_above = acc->sum_above[b];
  if (B1 < 1024) {   // k-th value negative: only nonneg values count (all above)
    if (tid == 0) acc->per_img[b] = (pos_sum + sum_above) / fmaxf((float)npos, 1.0f);
    return;
  }
  const int S = acc->list_cnt[b];
  const float* lb = list + (size_t)b*AA;
  const int cnt_above = acc->cnt_above[b];
  const int kt2 = k - cnt_above;   // rank target within bin B1, >= 1

  __shared__ int h[2048];
  __shared__ int sB2, sC2, sB3, sC3;
  h[tid] = 0; h[tid + 1024] = 0;
  __syncthreads();
  // level 2: key bits 20..10
  for (int i0 = 0; i0 < S; i0 += 1024) {
    const int i = i0 + tid;
    const int bin = (i < S) ? (int)((fkey(lb[i]) >> 10) & 0x7FF) : -1;
    agg_lds_add(h, bin);
  }
  __syncthreads();
  suffix_find_1024(h, 2048, kt2, &sB2, &sC2);
  const int B2 = sB2, cnt2 = sC2;
  const int kt3 = kt2 - cnt2;      // >= 1
  __syncthreads();
  h[tid] = 0;                      // reuse first 1024 bins for level 3
  __syncthreads();
  float msum = 0.0f; int mcnt = 0;
  for (int i0 = 0; i0 < S; i0 += 1024) {
    const int i = i0 + tid;
    int bin = -1;
    if (i < S) {
      const float v = lb[i];
      const unsigned key = fkey(v);
      const int sub = (int)((key >> 10) & 0x7FF);
      if (sub > B2) { msum += v; mcnt++; }
      else if (sub == B2) bin = (int)(key & 0x3FF);
    }
    agg_lds_add(h, bin);
  }
  __syncthreads();
  suffix_find_1024(h, 1024, kt3, &sB3, &sC3);
  const int B3 = sB3;
  const unsigned Kstar = ((unsigned)B1 << 21) | ((unsigned)B2 << 10) | (unsigned)B3;
  const float v = fkey_inv(Kstar);   // >= 0 since B1 >= 1024
  for (int i0 = 0; i0 < S; i0 += 1024) {
    const int i = i0 + tid;
    if (i < S) {
      const float x = lb[i];
      const unsigned key = fkey(x);
      if ((int)((key >> 10) & 0x7FF) == B2 && (int)(key & 0x3FF) > B3) { msum += x; mcnt++; }
    }
  }
  const int cg = redI1024(mcnt);
  const float sg = redF1024(msum);
  if (tid == 0) {
    const int total_gt = cnt_above + cg;   // all keys > Kstar
    const float ns = sum_above + sg + (float)(k - total_gt) * v;
    acc->per_img[b] = (pos_sum + ns) / fmaxf((float)npos, 1.0f);
  }
}

__global__ void k5_final(const Accum* __restrict__ acc, float* __restrict__ out) {
  float s = 0.0f; int tot = 0;
  for (int b = 0; b < BB; ++b) { s += acc->per_img[b]; tot += acc->npos[b]; }
  out[0] = s / (float)BB;
  const float denom = fmaxf((float)tot, 1.0f);
  out[1] = acc->shape_sum / (denom * 3.0f);
  out[2] = acc->off_sum / (denom * 3.0f);
  out[3] = 1.0f - acc->iou_sum / denom;
}

extern "C" void kernel_launch(void* const* d_in, const int* in_sizes, int n_in,
                              void* d_out, int out_size, void* d_ws, size_t ws_size,
                              hipStream_t stream) {
  const float* cls_out    = (const float*)d_in[0];
  const float* shape_out  = (const float*)d_in[1];
  const float* offset_out = (const float*)d_in[2];
  const float* ann        = (const float*)d_in[3];
  float* out = (float*)d_out;

  char* ws = (char*)d_ws;
  Accum* acc    = (Accum*)ws;                              // < 1 KB
  int* pos_n    = (int*)(ws + 1024);                       // 3.54 MB
  unsigned* ign = (unsigned*)(pos_n + (size_t)BB*AA);      // 110.6 KB
  float* neg    = (float*)(ign + (size_t)BB*AW);           // 3.54 MB
  int* ghist    = (int*)(neg + (size_t)BB*AA);             // 128 KB
  float* list   = (float*)pos_n;   // reuse: pos_n dead after k3

  const int n0 = N_POS4 + N_IGN4 + N_HIST4;                // 236288 -> 923 blocks
  hipLaunchKernelGGL(k0_init, dim3(n0/256), dim3(256), 0, stream,
                     (int4*)pos_n, (uint4*)ign, (int4*)ghist, acc);
  hipLaunchKernelGGL(k2_topk, dim3(BB*NN), dim3(256), 0, stream, ann, pos_n, ign);
  hipLaunchKernelGGL(k3_loss, dim3((BB*AA)/256), dim3(256), 0, stream,
                     cls_out, shape_out, offset_out, ann, pos_n, ign, neg, ghist, acc);
  hipLaunchKernelGGL(ks1, dim3(BB), dim3(256), 0, stream, ghist, acc);
  hipLaunchKernelGGL(kgather, dim3((BB*AA)/256), dim3(256), 0, stream, neg, list, acc);
  hipLaunchKernelGGL(ksel, dim3(BB), dim3(1024), 0, stream, list, acc);
  hipLaunchKernelGGL(k5_final, dim3(1), dim3(1), 0, stream, acc, out);
}

// Round 8
// 69.599 us; speedup vs baseline: 3.2939x; 3.0145x over previous
//
#include <hip/hip_runtime.h>

#define BB 16
#define NN 8
#define DD 24
#define HH 48
#define WW 48
#define AA (DD*HH*WW)   // 55296
#define AW (AA/32)      // 1728 ignore-bitmask words per image
#define NSEG (AA/256)   // 216 segments per image
#define TOPKc 7
#define KIGN 189        // (IGNORE_RATIO+1)*TOPK
#define NB1 2048        // level-1 bins = key >> 21
#define DCAP 16384      // dense survivor cap in LDS (64 KB)

// fixed candidate window (shifted to stay in-grid): 13 x 25 x 25 = 8125
#define WZC 13
#define WYC 25
#define WXC 25
#define WYXC (WYC*WXC)          // 625
#define CNTC (WZC*WYXC)         // 8125
#define CPT 32                  // 32*256 = 8192 >= 8125

struct GT {
  float ctr[3];
  float half_[3];
  float bbox[6];
  float lo[3], hi[3];
  int keep, rejected;
};

struct Accum {
  int   npos[BB];
  float pos_sum[BB];
  float shape_sum, off_sum, iou_sum;
  int   B1[BB];        // level-1 crossing bin (key>>21)
  int   cnt_above[BB]; // # elems in bins strictly above B1
  float per_img[BB];
};

__device__ __forceinline__ unsigned fkey(float f) {
  unsigned u = __float_as_uint(f);
  return (u & 0x80000000u) ? ~u : (u | 0x80000000u);
}
__device__ __forceinline__ float fkey_inv(unsigned k) {
  return __uint_as_float((k & 0x80000000u) ? (k & 0x7FFFFFFFu) : ~k);
}

// Wave-aggregated LDS histogram add (for SKEWED bins only, e.g. loss values).
__device__ __forceinline__ void agg_lds_add(int* h, int bin) {
  const int lane = threadIdx.x & 63;
  unsigned long long todo = __ballot(bin >= 0);
  while (todo) {
    const int leader = __ffsll((unsigned long long)todo) - 1;
    const int lbin = __shfl(bin, leader, 64);
    const unsigned long long eq = __ballot(bin == lbin) & todo;
    if (lane == leader) atomicAdd(&h[lbin], (int)__popcll(eq));
    todo &= ~eq;
  }
}

__device__ __forceinline__ GT prep_gt(const float* __restrict__ p) {
  const float cz=p[0], cy=p[1], cx=p[2], sz=p[3], sy=p[4], sx=p[5], label=p[6];
  const bool has_box = label > -1.0f;
  const float loz = fmaxf(cz - sz*0.5f, 0.0f);
  const float loy = fmaxf(cy - sy*0.5f, 0.0f);
  const float lox = fmaxf(cx - sx*0.5f, 0.0f);
  const float hiz = fminf(cz + sz*0.5f, 96.0f);
  const float hiy = fminf(cy + sy*0.5f, 192.0f);
  const float hix = fminf(cx + sx*0.5f, 192.0f);
  const float nz = fmaxf(hiz - loz, 0.0f);
  const float ny = fmaxf(hiy - loy, 0.0f);
  const float nx = fmaxf(hix - lox, 0.0f);
  const float vol = nz * ny * nx;
  const float percent = vol / (sz * sy * sx);
  const bool good = (percent > 0.1f) && (vol >= 15.0f);
  const bool keep = has_box && (vol > 0.0f) && good;
  const bool rejected = has_box && (vol > 0.0f) && !good;
  GT g;
  const float ncz = loz + nz*0.5f, ncy = loy + ny*0.5f, ncx = lox + nx*0.5f;
  if (keep) {
    g.ctr[0]=ncz*0.25f; g.ctr[1]=ncy*0.25f; g.ctr[2]=ncx*0.25f;
    g.half_[0]=nz*0.5f; g.half_[1]=ny*0.5f; g.half_[2]=nx*0.5f;
    g.bbox[0]=ncz; g.bbox[1]=ncy; g.bbox[2]=ncx;
    g.bbox[3]=nz;  g.bbox[4]=ny;  g.bbox[5]=nx;
  } else {
    for (int j=0;j<3;++j){ g.ctr[j]=-0.25f; g.half_[j]=-0.5f; }
    for (int j=0;j<6;++j) g.bbox[j]=-1.0f;
  }
  g.lo[0]=loz; g.lo[1]=loy; g.lo[2]=lox;
  g.hi[0]=hiz; g.hi[1]=hiy; g.hi[2]=hix;
  g.keep = keep ? 1 : 0;
  g.rejected = rejected ? 1 : 0;
  return g;
}

__device__ __forceinline__ int blockReduceSumI(int v) {
  __shared__ int s[4];
  for (int off = 32; off; off >>= 1) v += __shfl_down(v, off, 64);
  if ((threadIdx.x & 63) == 0) s[threadIdx.x >> 6] = v;
  __syncthreads();
  int r = s[0] + s[1] + s[2] + s[3];
  __syncthreads();
  return r;
}
__device__ __forceinline__ float blockReduceSumF(float v) {
  __shared__ float s[4];
  for (int off = 32; off; off >>= 1) v += __shfl_down(v, off, 64);
  if ((threadIdx.x & 63) == 0) s[threadIdx.x >> 6] = v;
  __syncthreads();
  float r = s[0] + s[1] + s[2] + s[3];
  __syncthreads();
  return r;
}
__device__ __forceinline__ int redI1024(int v) {
  __shared__ int s[16];
  for (int off = 32; off; off >>= 1) v += __shfl_down(v, off, 64);
  if ((threadIdx.x & 63) == 0) s[threadIdx.x >> 6] = v;
  __syncthreads();
  int r = 0;
  #pragma unroll
  for (int w = 0; w < 16; ++w) r += s[w];
  __syncthreads();
  return r;
}
__device__ __forceinline__ float redF1024(float v) {
  __shared__ float s[16];
  for (int off = 32; off; off >>= 1) v += __shfl_down(v, off, 64);
  if ((threadIdx.x & 63) == 0) s[threadIdx.x >> 6] = v;
  __syncthreads();
  float r = 0.0f;
  #pragma unroll
  for (int w = 0; w < 16; ++w) r += s[w];
  __syncthreads();
  return r;
}

// 1024-thread suffix-find over nbins (1024 or 2048) LDS bins.
__device__ void suffix_find_1024(const int* h, int nbins, int ktarget,
                                 int* s_bin, int* s_cnt) {
  const int tid = threadIdx.x, lane = tid & 63, wave = tid >> 6;
  const int C = nbins >> 10;
  int csum = 0;
  for (int i = 0; i < C; ++i) csum += h[tid*C + i];
  __shared__ int wt[16];
  int S = csum;
  #pragma unroll
  for (int off = 1; off < 64; off <<= 1) {
    const int t = __shfl_down(S, off, 64);
    if (lane + off < 64) S += t;
  }
  if (lane == 0) wt[wave] = S;
  __syncthreads();
  int above = 0;
  for (int w = wave + 1; w < 16; ++w) above += wt[w];
  const int sfx = above + (S - csum);
  if (sfx < ktarget && sfx + csum >= ktarget) {
    int running = sfx;
    for (int i = C - 1; i >= 0; --i) {
      const int c = h[tid*C + i];
      if (running + c >= ktarget) { *s_bin = tid*C + i; *s_cnt = running; break; }
      running += c;
    }
  }
  __syncthreads();
}

// segmented-list random access: i-th survivor of image (pfi inclusive prefix, cn counts)
__device__ __forceinline__ float seg_load(const float* lb, const int* pfi,
                                          const int* cn, int i) {
  int lo = 0, hi = NSEG - 1;
  while (lo < hi) { const int mid = (lo + hi) >> 1; if (pfi[mid] > i) hi = mid; else lo = mid + 1; }
  return lb[lo*256 + (i - (pfi[lo] - cn[lo]))];
}

#define N_POS4  (BB*AA/4)       // 221184
#define N_IGN4  (BB*AW/4)       // 6912
#define N_HIST4 (BB*NB1/4)      // 8192

__global__ __launch_bounds__(256) void k0_init(int4* pos_n4, uint4* ign4,
                                               int4* hist4, Accum* acc) {
  const int idx = blockIdx.x*256 + threadIdx.x;
  if (idx < N_POS4) {
    pos_n4[idx] = make_int4(0x7FFFFFFF,0x7FFFFFFF,0x7FFFFFFF,0x7FFFFFFF);
  } else if (idx < N_POS4 + N_IGN4) {
    ign4[idx - N_POS4] = make_uint4(0,0,0,0);
  } else if (idx < N_POS4 + N_IGN4 + N_HIST4) {
    hist4[idx - (N_POS4 + N_IGN4)] = make_int4(0,0,0,0);
  }
  if (idx < BB) {
    acc->npos[idx] = 0; acc->pos_sum[idx] = 0.0f;
    acc->B1[idx] = 0; acc->cnt_above[idx] = 0;
  }
  if (idx == 0) { acc->shape_sum = 0.0f; acc->off_sum = 0.0f; acc->iou_sum = 0.0f; }
}

// One block per (b,n). Histogram-select over the 13x25x25 window (provable
// superset of the top-189 ellipsoid). Keys recomputed per pass (bit-identical
// fmaf expression) -> no register arrays, no spill risk, ~6 barriers total.
__global__ __launch_bounds__(256) void k2_topk(const float* __restrict__ ann,
                                               int* __restrict__ pos_n,
                                               unsigned* __restrict__ ign) {
  const int bn = blockIdx.x;
  const int b = bn >> 3, n = bn & 7;
  const GT g = prep_gt(ann + bn*7);
  if (!g.keep) return;
  const float cz = g.ctr[0], cy = g.ctr[1], cx = g.ctr[2];
  const int rz = (int)floorf(cz + 0.5f);
  const int ry = (int)floorf(cy + 0.5f);
  const int rx = (int)floorf(cx + 0.5f);
  const int zlo = min(max(rz - 6, 0),  DD - WZC);
  const int ylo = min(max(ry - 12, 0), HH - WYC);
  const int xlo = min(max(rx - 12, 0), WW - WXC);
  const int tid = threadIdx.x;

  __shared__ int h[1024];            // valid keys are in [1, 0x7FFFFFFF] -> bin<1024
  #pragma unroll
  for (int i = 0; i < 4; ++i) h[tid + i*256] = 0;
  __syncthreads();

#define K2_KEYAID(J, KEY, AID, VALID)                                   \
  const int ci = tid + (J)*256;                                         \
  const bool VALID = ci < CNTC;                                         \
  const int wz = ci / WYXC;                                             \
  const int rem = ci - wz*WYXC;                                         \
  const int wy = rem / WXC;                                             \
  const int wx = rem - wy*WXC;                                          \
  const int z = zlo + wz, y = ylo + wy, x = xlo + wx;                   \
  const float dz = (cz - (float)z) * 2.0f;                              \
  const float dy = cy - (float)y;                                       \
  const float dx = cx - (float)x;                                      \
  const unsigned KEY = fkey(-__builtin_fmaf(dz, dz, __builtin_fmaf(dy, dy, dx*dx))); \
  const int AID = (z*HH + y)*WW + x;

  // pass A: histogram (bins mostly distinct within a wave -> plain LDS atomic)
  #pragma unroll
  for (int j = 0; j < CPT; ++j) {
    K2_KEYAID(j, key, aid, valid)
    (void)aid;
    if (valid) atomicAdd(&h[key >> 21], 1);
  }
  __syncthreads();

  // suffix scan: find crossing bins for rank 7 and rank 189 in one pass
  __shared__ int wt[4];
  __shared__ int sB7, sA7, sB9, sA9;
  const int lane = tid & 63, wave = tid >> 6;
  int csum = 0;
  #pragma unroll
  for (int i = 0; i < 4; ++i) csum += h[tid*4 + i];
  int Ssc = csum;
  #pragma unroll
  for (int off = 1; off < 64; off <<= 1) {
    const int t = __shfl_down(Ssc, off, 64);
    if (lane + off < 64) Ssc += t;
  }
  if (lane == 0) wt[wave] = Ssc;
  __syncthreads();
  int above = 0;
  for (int w = wave + 1; w < 4; ++w) above += wt[w];
  const int sfx = above + (Ssc - csum);
  if (sfx < TOPKc && sfx + csum >= TOPKc) {
    int run = sfx;
    for (int i = 3; i >= 0; --i) {
      const int c = h[tid*4 + i];
      if (run + c >= TOPKc) { sB7 = tid*4 + i; sA7 = run; break; }
      run += c;
    }
  }
  if (sfx < KIGN && sfx + csum >= KIGN) {
    int run = sfx;
    for (int i = 3; i >= 0; --i) {
      const int c = h[tid*4 + i];
      if (run + c >= KIGN) { sB9 = tid*4 + i; sA9 = run; break; }
      run += c;
    }
  }
  __syncthreads();
  const int B7 = sB7, A7 = sA7, B9 = sB9, A9 = sA9;

  // pass B: collect keys of crossing bins
  __shared__ unsigned kl7[512], kl9[512];
  __shared__ int n7s, n9s;
  if (tid == 0) { n7s = 0; n9s = 0; }
  __syncthreads();
  #pragma unroll
  for (int j = 0; j < CPT; ++j) {
    K2_KEYAID(j, key, aid, valid)
    (void)aid;
    if (valid) {
      const int bin = (int)(key >> 21);
      if (bin == B7) { const int p = atomicAdd(&n7s, 1); if (p < 512) kl7[p] = key; }
      if (bin == B9 && B9 != B7) { const int p = atomicAdd(&n9s, 1); if (p < 512) kl9[p] = key; }
    }
  }
  __syncthreads();

  // exact k-th key within crossing bin (O(L^2), L small)
  __shared__ unsigned sk7, sk9;
  __shared__ int scg7, scg9;
  const int T7c = min(n7s, 512), T9c = min(n9s, 512);
  for (int i = tid; i < T7c; i += 256) {
    const unsigned xv = kl7[i];
    int gt = 0, eq = 0;
    for (int j2 = 0; j2 < T7c; ++j2) { gt += (kl7[j2] > xv); eq += (kl7[j2] == xv); }
    if (A7 + gt < TOPKc && TOPKc <= A7 + gt + eq) { sk7 = xv; scg7 = A7 + gt; }
    if (B9 == B7 && A7 + gt < KIGN && KIGN <= A7 + gt + eq) { sk9 = xv; scg9 = A7 + gt; }
  }
  if (B9 != B7) {
    for (int i = tid; i < T9c; i += 256) {
      const unsigned xv = kl9[i];
      int gt = 0, eq = 0;
      for (int j2 = 0; j2 < T9c; ++j2) { gt += (kl9[j2] > xv); eq += (kl9[j2] == xv); }
      if (A9 + gt < KIGN && KIGN <= A9 + gt + eq) { sk9 = xv; scg9 = A9 + gt; }
    }
  }
  __syncthreads();
  const unsigned k7 = sk7, k9 = sk9;
  const int cg7 = scg7, cg9 = scg9;

  // pass C: boundary-tie lists (anchor ids with key == k-th key), index-ranked
  __shared__ int tc7, tc9;
  __shared__ int tl7[256], tr7[256], tl9[256], tr9[256];
  if (tid == 0) { tc7 = 0; tc9 = 0; }
  __syncthreads();
  #pragma unroll
  for (int j = 0; j < CPT; ++j) {
    K2_KEYAID(j, key, aid, valid)
    if (valid) {
      if (key == k7) { const int p = atomicAdd(&tc7, 1); if (p < 256) tl7[p] = aid; }
      if (key == k9 && k9 != k7) { const int p = atomicAdd(&tc9, 1); if (p < 256) tl9[p] = aid; }
    }
  }
  __syncthreads();
  const int T7 = min(tc7, 256), T9 = min(tc9, 256);
  for (int i = tid; i < T7; i += 256) {
    const int ai = tl7[i]; int r = 0;
    for (int j2 = 0; j2 < T7; ++j2) r += (tl7[j2] < ai);
    tr7[i] = r;
  }
  for (int i = tid; i < T9; i += 256) {
    const int ai = tl9[i]; int r = 0;
    for (int j2 = 0; j2 < T9; ++j2) r += (tl9[j2] < ai);
    tr9[i] = r;
  }
  __syncthreads();

  // pass D: mark
  int* pb = pos_n + (size_t)b*AA;
  unsigned* ib = ign + (size_t)b*AW;
  #pragma unroll
  for (int j = 0; j < CPT; ++j) {
    K2_KEYAID(j, key, aid, valid)
    if (valid) {
      bool top = false, igf = false;
      if (key > k7) top = true;
      else if (key == k7) {
        int r = 0;
        for (int t = 0; t < T7; ++t) if (tl7[t] == aid) r = tr7[t];
        const int ov = cg7 + r;
        if (ov < TOPKc) top = true;
        else if (ov < KIGN) igf = true;
      } else if (key > k9) igf = true;
      else if (key == k9) {
        int r = 0;
        for (int t = 0; t < T9; ++t) if (tl9[t] == aid) r = tr9[t];
        if (cg9 + r < KIGN) igf = true;
      }
      if (top) atomicMin(&pb[aid], n);
      else if (igf) atomicOr(&ib[aid >> 5], 1u << (aid & 31));
    }
  }
#undef K2_KEYAID
}

// Per-anchor losses + per-block LDS level-1 histogram, sparse-merged to global.
__global__ __launch_bounds__(256) void k3_loss(
    const float* __restrict__ cls_out, const float* __restrict__ shape_out,
    const float* __restrict__ offset_out, const float* __restrict__ ann,
    const int* __restrict__ pos_n, const unsigned* __restrict__ ignm,
    float* __restrict__ neg, int* __restrict__ ghist, Accum* acc) {
  __shared__ GT sg[NN];
  __shared__ int h1[NB1];
  const int idx = blockIdx.x * 256 + threadIdx.x;
  const int b = idx / AA;
  const int a = idx - b * AA;
  if (threadIdx.x < NN) sg[threadIdx.x] = prep_gt(ann + (b*NN + threadIdx.x)*7);
  #pragma unroll
  for (int i = 0; i < NB1/256; ++i) h1[threadIdx.x + i*256] = 0;
  __syncthreads();
  const int z = a / (HH*WW);
  const int rr = a - z*(HH*WW);
  const int y = rr / WW;
  const int x = rr - y*WW;

  float gign = 0.0f;
  for (int n = 0; n < NN; ++n) {
    if (!sg[n].rejected) continue;
    if ((float)z >= floorf(sg[n].lo[0]) && (float)z < ceilf(sg[n].hi[0]) &&
        (float)y >= floorf(sg[n].lo[1]) && (float)y < ceilf(sg[n].hi[1]) &&
        (float)x >= floorf(sg[n].lo[2]) && (float)x < ceilf(sg[n].hi[2])) gign = -1.0f;
  }

  const int pn = pos_n[idx];
  const bool is_pos = (pn < NN);
  const float target = is_pos ? 1.0f : 0.0f;
  const int ibit = (ignm[b*AW + (a >> 5)] >> (a & 31)) & 1;
  const float ignore = (ibit ? -1.0f : 0.0f) + gign;
  const float pred = cls_out[idx];
  float prob = 1.0f / (1.0f + expf(-pred));
  prob = fminf(fmaxf(prob, 1e-4f), 1.0f - 1e-4f);
  const float alpha_f = is_pos ? 0.75f : 0.25f;
  const float pt = is_pos ? (1.0f - prob) : prob;
  const float fw = alpha_f * pt * pt;
  const float bce = fmaxf(pred, 0.0f) + log1pf(expf(-fabsf(pred))) - pred * target;
  float loss = (ignore == 0.0f) ? fw * bce : 0.0f;
  if (prob < 0.8f && is_pos) loss *= 4.0f;
  const float nval = is_pos ? -1.0f : loss;
  neg[idx] = nval;

  agg_lds_add(h1, (int)(fkey(nval) >> 21));   // skewed -> aggregated

  const int np = blockReduceSumI(is_pos ? 1 : 0);
  const float ps = blockReduceSumF(is_pos ? loss : 0.0f);
  if (threadIdx.x == 0 && np) {
    atomicAdd(&acc->npos[b], np);
    atomicAdd(&acc->pos_sum[b], ps);
  }

  if (is_pos) {
    const GT& g = sg[pn];
    const float toz = g.ctr[0] - (float)z;
    const float toy = g.ctr[1] - (float)y;
    const float tox = g.ctr[2] - (float)x;
    const float poz = offset_out[((size_t)b*3 + 0)*AA + a];
    const float poy = offset_out[((size_t)b*3 + 1)*AA + a];
    const float pox = offset_out[((size_t)b*3 + 2)*AA + a];
    const float psz = shape_out[((size_t)b*3 + 0)*AA + a];
    const float psy = shape_out[((size_t)b*3 + 1)*AA + a];
    const float psx = shape_out[((size_t)b*3 + 2)*AA + a];
    const float off_t = fabsf(poz - toz) + fabsf(poy - toy) + fabsf(pox - tox);
    const float shp_t = fabsf(psz - g.half_[0]) + fabsf(psy - g.half_[1]) + fabsf(psx - g.half_[2]);
    const float c1z = ((float)z + poz) * 4.0f;
    const float c1y = ((float)y + poy) * 4.0f;
    const float c1x = ((float)x + pox) * 4.0f;
    const float s1z = 2.0f*psz, s1y = 2.0f*psy, s1x = 2.0f*psx;
    const float lo1z = c1z - s1z*0.5f, hi1z = c1z + s1z*0.5f;
    const float lo1y = c1y - s1y*0.5f, hi1y = c1y + s1y*0.5f;
    const float lo1x = c1x - s1x*0.5f, hi1x = c1x + s1x*0.5f;
    const float c2z = g.bbox[0], c2y = g.bbox[1], c2x = g.bbox[2];
    const float s2z = g.bbox[3], s2y = g.bbox[4], s2x = g.bbox[5];
    const float lo2z = c2z - s2z*0.5f, hi2z = c2z + s2z*0.5f;
    const float lo2y = c2y - s2y*0.5f, hi2y = c2y + s2y*0.5f;
    const float lo2x = c2x - s2x*0.5f, hi2x = c2x + s2x*0.5f;
    const float iz = fmaxf(fminf(hi1z,hi2z) - fmaxf(lo1z,lo2z), 0.0f);
    const float iy = fmaxf(fminf(hi1y,hi2y) - fmaxf(lo1y,lo2y), 0.0f);
    const float ix = fmaxf(fminf(hi1x,hi2x) - fmaxf(lo1x,lo2x), 0.0f);
    const float inter = iz*iy*ix + 1e-7f;
    const float uni = s1z*s1y*s1x + s2z*s2y*s2x - inter;
    const float iou = inter / uni;
    const float ez = fmaxf(hi1z,hi2z) - fminf(lo1z,lo2z);
    const float ey = fmaxf(hi1y,hi2y) - fminf(lo1y,lo2y);
    const float ex = fmaxf(hi1x,hi2x) - fminf(lo1x,lo2x);
    const float c2d = (ez*ez + ey*ey) + ex*ex + 1e-7f;
    const float rz2 = (lo2z + hi2z) - (lo1z + hi1z);
    const float ry2 = (lo2y + hi2y) - (lo1y + hi1y);
    const float rx2 = (lo2x + hi2x) - (lo1x + hi1x);
    const float rho2 = ((rz2*rz2 + ry2*ry2) + rx2*rx2) * 0.25f;
    const float diou = iou - rho2 / c2d;
    atomicAdd(&acc->shape_sum, shp_t);
    atomicAdd(&acc->off_sum, off_t);
    atomicAdd(&acc->iou_sum, diou);
  }

  __syncthreads();
  #pragma unroll
  for (int i = 0; i < NB1/256; ++i) {
    const int bin = threadIdx.x + i*256;
    const int c = h1[bin];
    if (c) atomicAdd(&ghist[b*NB1 + bin], c);
  }
}

// One block per image: suffix-scan of 2048 global bins -> B1 + count above.
__global__ __launch_bounds__(256) void ks1(const int* __restrict__ ghist, Accum* acc) {
  const int b = blockIdx.x;
  const int* hb = ghist + b*NB1;
  const int tid = threadIdx.x, lane = tid & 63, wave = tid >> 6;
  const int npos = acc->npos[b];
  const int k = npos > 0 ? 100*npos : 100;
  int csum = 0;
  #pragma unroll
  for (int i = 0; i < 8; ++i) csum += hb[tid*8 + i];
  __shared__ int wt[4];
  int S = csum;
  #pragma unroll
  for (int off = 1; off < 64; off <<= 1) {
    const int t = __shfl_down(S, off, 64);
    if (lane + off < 64) S += t;
  }
  if (lane == 0) wt[wave] = S;
  __syncthreads();
  int above = 0;
  for (int w = wave + 1; w < 4; ++w) above += wt[w];
  const int sfx = above + (S - csum);
  if (sfx < k && sfx + csum >= k) {
    int running = sfx;
    for (int i = 7; i >= 0; --i) {
      const int c = hb[tid*8 + i];
      if (running + c >= k) {
        acc->B1[b] = tid*8 + i;
        acc->cnt_above[b] = running;
        break;
      }
      running += c;
    }
  }
}

// Full-chip, ATOMIC-FREE: per-segment compaction of bin-B1 survivors (ballot
// order = anchor order, deterministic) + per-block partial sum of above-B1.
__global__ __launch_bounds__(256) void kgather(const float* __restrict__ neg,
                                               float* __restrict__ list,
                                               float* __restrict__ psum,
                                               int* __restrict__ seg_cnt,
                                               const Accum* __restrict__ acc) {
  const int idx = blockIdx.x*256 + threadIdx.x;
  const int b = idx / AA;
  const int seg = (idx - b*AA) >> 8;
  const int tid = threadIdx.x, lane = tid & 63, wave = tid >> 6;
  const int B1 = acc->B1[b];
  const float val = neg[idx];
  const int bin = (int)(fkey(val) >> 21);
  const float aval = (bin > B1 && bin >= 1024) ? val : 0.0f;
  const float bs = blockReduceSumF(aval);

  const bool match = (bin == B1);
  const unsigned long long mask = __ballot(match);
  __shared__ int wc[4];
  if (lane == 0) wc[wave] = (int)__popcll(mask);
  __syncthreads();
  int wbase = 0;
  for (int w = 0; w < wave; ++w) wbase += wc[w];
  if (match) {
    const int pos = (int)__popcll(mask & ((1ull << lane) - 1ull));
    list[(size_t)b*AA + seg*256 + wbase + pos] = val;
  }
  if (tid == 0) {
    psum[b*NSEG + seg] = bs;
    seg_cnt[b*NSEG + seg] = wc[0] + wc[1] + wc[2] + wc[3];
  }
}

// One block per image: exact refinement of remaining 21 key bits over the
// (LDS-dense) survivor list; deterministic sum_above reduce from psum.
__global__ __launch_bounds__(1024) void ksel(const float* __restrict__ list,
                                             const float* __restrict__ psum,
                                             const int* __restrict__ seg_cnt,
                                             Accum* acc) {
  const int b = blockIdx.x;
  const int tid = threadIdx.x;
  const int npos = acc->npos[b];
  const int k = npos > 0 ? 100*npos : 100;
  const int B1 = acc->B1[b];
  const float pos_sum = acc->pos_sum[b];

  const float pv = (tid < NSEG) ? psum[b*NSEG + tid] : 0.0f;
  const float sum_above = redF1024(pv);

  if (B1 < 1024) {   // k-th value negative: only nonneg values counted
    if (tid == 0) acc->per_img[b] = (pos_sum + sum_above) / fmaxf((float)npos, 1.0f);
    return;
  }

  __shared__ int cn[NSEG];
  __shared__ int pfi[256];
  if (tid < 256) {
    const int c = (tid < NSEG) ? seg_cnt[b*NSEG + tid] : 0;
    if (tid < NSEG) cn[tid] = c;
    pfi[tid] = c;
  }
  __syncthreads();
  for (int off = 1; off < 256; off <<= 1) {
    int v = 0;
    if (tid < 256 && tid >= off) v = pfi[tid - off];
    __syncthreads();
    if (tid < 256) pfi[tid] += v;
    __syncthreads();
  }
  const int S = pfi[NSEG - 1];
  const int cnt_above = acc->cnt_above[b];
  const int kt2 = k - cnt_above;     // >= 1
  const float* lb = list + (size_t)b*AA;

  __shared__ float ld[DCAP];
  const bool fits = (S <= DCAP);
  if (fits) {
    for (int i = tid; i < S; i += 1024) ld[i] = seg_load(lb, pfi, cn, i);
  }
  __syncthreads();

  __shared__ int h[2048];
  __shared__ int sB2, sC2, sB3, sC3;
  h[tid] = 0; h[tid + 1024] = 0;
  __syncthreads();
  // level 2: key bits 20..10
  for (int i0 = 0; i0 < S; i0 += 1024) {
    const int i = i0 + tid;
    if (i < S) {
      const float v = fits ? ld[i] : seg_load(lb, pfi, cn, i);
      atomicAdd(&h[(fkey(v) >> 10) & 0x7FF], 1);
    }
  }
  __syncthreads();
  suffix_find_1024(h, 2048, kt2, &sB2, &sC2);
  const int B2 = sB2;
  const int kt3 = kt2 - sC2;         // >= 1
  h[tid < 1024 ? tid : 0] = (tid < 1024) ? 0 : h[0];  // reset first 1024 bins
  __syncthreads();
  // level 3: key bits 9..0 among (B1,B2); also accumulate msum for sub > B2
  float msum = 0.0f; int mcnt = 0;
  for (int i0 = 0; i0 < S; i0 += 1024) {
    const int i = i0 + tid;
    if (i < S) {
      const float v = fits ? ld[i] : seg_load(lb, pfi, cn, i);
      const unsigned key = fkey(v);
      const int sub = (int)((key >> 10) & 0x7FF);
      if (sub > B2) { msum += v; mcnt++; }
      else if (sub == B2) atomicAdd(&h[key & 0x3FF], 1);
    }
  }
  __syncthreads();
  suffix_find_1024(h, 1024, kt3, &sB3, &sC3);
  const int B3 = sB3;
  const unsigned Kstar = ((unsigned)B1 << 21) | ((unsigned)B2 << 10) | (unsigned)B3;
  const float v = fkey_inv(Kstar);   // >= 0 since B1 >= 1024
  for (int i0 = 0; i0 < S; i0 += 1024) {
    const int i = i0 + tid;
    if (i < S) {
      const float x = fits ? ld[i] : seg_load(lb, pfi, cn, i);
      const unsigned key = fkey(x);
      if ((int)((key >> 10) & 0x7FF) == B2 && (int)(key & 0x3FF) > B3) { msum += x; mcnt++; }
    }
  }
  const int cg = redI1024(mcnt);
  const float sg = redF1024(msum);
  if (tid == 0) {
    const int total_gt = cnt_above + cg;
    const float ns = sum_above + sg + (float)(k - total_gt) * v;
    acc->per_img[b] = (pos_sum + ns) / fmaxf((float)npos, 1.0f);
  }
}

__global__ void k5_final(const Accum* __restrict__ acc, float* __restrict__ out) {
  float s = 0.0f; int tot = 0;
  for (int b = 0; b < BB; ++b) { s += acc->per_img[b]; tot += acc->npos[b]; }
  out[0] = s / (float)BB;
  const float denom = fmaxf((float)tot, 1.0f);
  out[1] = acc->shape_sum / (denom * 3.0f);
  out[2] = acc->off_sum / (denom * 3.0f);
  out[3] = 1.0f - acc->iou_sum / denom;
}

extern "C" void kernel_launch(void* const* d_in, const int* in_sizes, int n_in,
                              void* d_out, int out_size, void* d_ws, size_t ws_size,
                              hipStream_t stream) {
  const float* cls_out    = (const float*)d_in[0];
  const float* shape_out  = (const float*)d_in[1];
  const float* offset_out = (const float*)d_in[2];
  const float* ann        = (const float*)d_in[3];
  float* out = (float*)d_out;

  char* ws = (char*)d_ws;
  Accum* acc    = (Accum*)ws;                              // < 1 KB
  int* pos_n    = (int*)(ws + 1024);                       // 3.54 MB
  unsigned* ign = (unsigned*)(pos_n + (size_t)BB*AA);      // 110.6 KB
  float* neg    = (float*)(ign + (size_t)BB*AW);           // 3.54 MB
  int* ghist    = (int*)(neg + (size_t)BB*AA);             // 128 KB
  float* psum   = (float*)(ghist + (size_t)BB*NB1);        // 13.8 KB
  int* seg_cnt  = (int*)(psum + (size_t)BB*NSEG);          // 13.8 KB
  float* list   = (float*)pos_n;   // reuse: pos_n dead after k3

  const int n0 = N_POS4 + N_IGN4 + N_HIST4;                // 236288 -> 923 blocks
  hipLaunchKernelGGL(k0_init, dim3(n0/256), dim3(256), 0, stream,
                     (int4*)pos_n, (uint4*)ign, (int4*)ghist, acc);
  hipLaunchKernelGGL(k2_topk, dim3(BB*NN), dim3(256), 0, stream, ann, pos_n, ign);
  hipLaunchKernelGGL(k3_loss, dim3((BB*AA)/256), dim3(256), 0, stream,
                     cls_out, shape_out, offset_out, ann, pos_n, ign, neg, ghist, acc);
  hipLaunchKernelGGL(ks1, dim3(BB), dim3(256), 0, stream, ghist, acc);
  hipLaunchKernelGGL(kgather, dim3((BB*AA)/256), dim3(256), 0, stream,
                     neg, list, psum, seg_cnt, acc);
  hipLaunchKernelGGL(ksel, dim3(BB), dim3(1024), 0, stream, list, psum, seg_cnt, acc);
  hipLaunchKernelGGL(k5_final, dim3(1), dim3(1), 0, stream, acc, out);
}